// Round 21
// baseline (415.840 us; speedup 1.0000x reference)
//
#include <hip/hip_runtime.h>
#include <cstdint>
#include <cstddef>

typedef __bf16 bf16x8 __attribute__((ext_vector_type(8)));
typedef __bf16 bf16x4 __attribute__((ext_vector_type(4)));
typedef float  f32x4  __attribute__((ext_vector_type(4)));

#define S_TXT 256
#define S_IMG 2048
#define S_TOT 2304
#define NHEAD 24
#define HDIM  128
#define DMODEL 3072

static constexpr size_t SZ_QKV  = (size_t)NHEAD * S_TOT * HDIM;   // 7,077,888
static constexpr size_t SZ_AO   = (size_t)S_TOT * DMODEL;         // 7,077,888
static constexpr size_t SZ_XIMG = (size_t)S_IMG * DMODEL;
static constexpr size_t SZ_XTXT = (size_t)S_TXT * DMODEL;
static constexpr size_t SZ_W    = (size_t)DMODEL * DMODEL;        // 9,437,184

// 1/sqrt(128) * log2(e): flash softmax runs in base-2 (native v_exp_f32)
#define QSCALE (0.08838834764831845f * 1.4426950408889634f)

__device__ __forceinline__ f32x4 mfma16(bf16x8 a, bf16x8 b, f32x4 c) {
  return __builtin_amdgcn_mfma_f32_16x16x32_bf16(a, b, c, 0, 0, 0);
}

__device__ __forceinline__ float fexp2(float x) {
  return __builtin_amdgcn_exp2f(x);
}

// ---------------- fp32 -> bf16 convert (RNE) ----------------
__global__ __launch_bounds__(256) void cvt_f32_bf16(const float* __restrict__ in,
                                                    __bf16* __restrict__ out, int n) {
  int i = (blockIdx.x * 256 + threadIdx.x) * 8;
  if (i + 8 > n) return;
  f32x4 a = *(const f32x4*)(in + i);
  f32x4 b = *(const f32x4*)(in + i + 4);
  bf16x8 r;
  r[0]=(__bf16)a[0]; r[1]=(__bf16)a[1]; r[2]=(__bf16)a[2]; r[3]=(__bf16)a[3];
  r[4]=(__bf16)b[0]; r[5]=(__bf16)b[1]; r[6]=(__bf16)b[2]; r[7]=(__bf16)b[3];
  *(bf16x8*)(out + i) = r;
}

// ------ multi-weight fp32 -> bf16, grid-strided (G11: ~1K blocks + stride) ------
// grid (1152, nw): per weight 9,437,184 elems = 1152*256*8 * 4 -> exactly 4 iters.
struct CWArgs { const float* s[8]; __bf16* d[8]; };
__global__ __launch_bounds__(256) void cvt_w(CWArgs a) {
  const float* in = a.s[blockIdx.y];
  __bf16* out = a.d[blockIdx.y];
  const size_t stride = (size_t)gridDim.x * 256 * 8;
  for (size_t i = ((size_t)blockIdx.x * 256 + threadIdx.x) * 8; i < SZ_W; i += stride) {
    f32x4 x = *(const f32x4*)(in + i);
    f32x4 y = *(const f32x4*)(in + i + 4);
    bf16x8 r;
    r[0]=(__bf16)x[0]; r[1]=(__bf16)x[1]; r[2]=(__bf16)x[2]; r[3]=(__bf16)x[3];
    r[4]=(__bf16)y[0]; r[5]=(__bf16)y[1]; r[6]=(__bf16)y[2]; r[7]=(__bf16)y[3];
    *(bf16x8*)(out + i) = r;
  }
}

// ---------------- RoPE in-place; Q additionally pre-scaled by QSCALE ----------------
__global__ __launch_bounds__(256) void rope_kernel(__bf16* __restrict__ Qb, __bf16* __restrict__ Kb,
    const float* __restrict__ icos, const float* __restrict__ isin,
    const float* __restrict__ tcos, const float* __restrict__ tsin) {
  size_t idx = ((size_t)blockIdx.x * 256 + threadIdx.x) * 8;
  __bf16* X; float mult;
  if (blockIdx.y) { X = Kb; mult = 1.0f; }
  else            { X = Qb; mult = QSCALE; }
  int d = (int)(idx & 127);
  int s = (int)((idx >> 7) % S_TOT);
  const float *cp, *sp; int ss;
  if (s < S_TXT) { cp = tcos; sp = tsin; ss = s; }
  else           { cp = icos; sp = isin; ss = s - S_TXT; }
  const float* cb = cp + (size_t)ss * HDIM + d;
  const float* sb = sp + (size_t)ss * HDIM + d;
  f32x4 c0 = *(const f32x4*)(cb);
  f32x4 c1 = *(const f32x4*)(cb + 4);
  f32x4 s0 = *(const f32x4*)(sb);
  f32x4 s1 = *(const f32x4*)(sb + 4);
  bf16x8 x = *(const bf16x8*)(X + idx);
  float xf[8];
  #pragma unroll
  for (int j = 0; j < 8; ++j) xf[j] = (float)x[j];
  bf16x8 o;
  o[0] = (__bf16)((xf[0]*c0[0] - xf[1]*s0[0]) * mult);
  o[1] = (__bf16)((xf[1]*c0[1] + xf[0]*s0[1]) * mult);
  o[2] = (__bf16)((xf[2]*c0[2] - xf[3]*s0[2]) * mult);
  o[3] = (__bf16)((xf[3]*c0[3] + xf[2]*s0[3]) * mult);
  o[4] = (__bf16)((xf[4]*c1[0] - xf[5]*s1[0]) * mult);
  o[5] = (__bf16)((xf[5]*c1[1] + xf[4]*s1[1]) * mult);
  o[6] = (__bf16)((xf[6]*c1[2] - xf[7]*s1[2]) * mult);
  o[7] = (__bf16)((xf[7]*c1[3] + xf[6]*s1[3]) * mult);
  *(bf16x8*)(X + idx) = o;
}

// ---------------- V [h][s][d] -> Vt [h][d][s] (FALLBACK PATH ONLY) ----------------
__global__ __launch_bounds__(128) void transpose_v(const __bf16* __restrict__ V,
                                                   __bf16* __restrict__ Vt) {
  int h = blockIdx.y, s0 = blockIdx.x * 64, d = threadIdx.x;
  const __bf16* src = V + ((size_t)h * S_TOT + s0) * HDIM + d;
  __bf16 tmp[64];
  #pragma unroll
  for (int k = 0; k < 64; ++k) tmp[k] = src[(size_t)k * HDIM];
  __bf16* dst = Vt + ((size_t)h * HDIM + d) * S_TOT + s0;
  #pragma unroll
  for (int k = 0; k < 8; ++k) {
    bf16x8 v;
    #pragma unroll
    for (int j = 0; j < 8; ++j) v[j] = tmp[k*8 + j];
    *(bf16x8*)(dst + k*8) = v;
  }
}

// ================ pure-bf16 GEMM (m97-faithful), BM=BN=128, BK=64 ================
struct GBArgs {
  const __bf16* A;
  const __bf16* W0[3];
  const __bf16* W1[3];
  const float* b0[3]; const float* b1[3];
  void* O0[3]; void* O1[3];
};

template<int MODE>
__global__ __launch_bounds__(256) void gemm_bf(GBArgs ga) {
  const int tid = threadIdx.x;
  const int lane = tid & 63, wave = tid >> 6;
  const int wr = wave >> 1, wc = wave & 1;
  const int g = lane >> 4, lr = lane & 15;
  const int x7 = lr & 7;

  const int hw = (int)blockIdx.x;
  const int xcd = hw & 7, idx = hw >> 3;
  const int bx = idx % 18;
  const int nglob = (MODE == 0) ? (xcd * 9 + idx / 18) : (xcd * 3 + idx / 18);
  const int wsel = (MODE == 0) ? nglob / 24 : 0;
  const int ny   = (MODE == 0) ? nglob % 24 : nglob;
  const int m0 = bx * 128;
  const int n0 = ny * 128;
  const bool txt = (MODE == 0) ? (m0 >= S_IMG) : (m0 < S_TXT);
  const __bf16* Wf  = txt ? ga.W1[wsel] : ga.W0[wsel];
  const float* bias = txt ? ga.b1[wsel] : ga.b0[wsel];

  __shared__ __align__(16) __bf16 As[128 * 64];
  __shared__ __align__(16) __bf16 Bs[128 * 64];

  const int sr8 = lane >> 3;
  const int sch = (lane & 7) ^ sr8;
  const __bf16* Ap = ga.A + (size_t)(m0 + wave * 8 + sr8) * DMODEL + sch * 8;
  const __bf16* Bp = Wf   + (size_t)(n0 + wave * 8 + sr8) * DMODEL + sch * 8;

  f32x4 acc[4][4];
  #pragma unroll
  for (int i = 0; i < 4; ++i)
    #pragma unroll
    for (int j = 0; j < 4; ++j) acc[i][j] = (f32x4){0.f,0.f,0.f,0.f};

#define GLD(dst, srcp) { \
    _Pragma("unroll") \
    for (int i_ = 0; i_ < 4; ++i_) \
      __builtin_amdgcn_global_load_lds( \
          (const __attribute__((address_space(1))) void*)((srcp) + (size_t)i_ * 32 * DMODEL), \
          (__attribute__((address_space(3))) void*)((char*)(dst) + i_ * 4096 + wave * 1024), \
          16, 0, 0); }

  for (int kt = 0; kt < DMODEL / 64; ++kt) {
    GLD(As, Ap + kt * 64);
    GLD(Bs, Bp + kt * 64);
    __syncthreads();
    #pragma unroll
    for (int ks = 0; ks < 2; ++ks) {
      bf16x8 af[4], bf[4];
      #pragma unroll
      for (int i = 0; i < 4; ++i)
        af[i] = *(const bf16x8*)((char*)As + (wr*64 + i*16 + lr) * 128 + (((ks*4 + g) ^ x7) << 4));
      #pragma unroll
      for (int j = 0; j < 4; ++j)
        bf[j] = *(const bf16x8*)((char*)Bs + (wc*64 + j*16 + lr) * 128 + (((ks*4 + g) ^ x7) << 4));
      __builtin_amdgcn_s_setprio(1);
      #pragma unroll
      for (int i = 0; i < 4; ++i)
        #pragma unroll
        for (int j = 0; j < 4; ++j)
          acc[i][j] = mfma16(af[i], bf[j], acc[i][j]);
      __builtin_amdgcn_s_setprio(0);
    }
    __syncthreads();
  }
#undef GLD

  float bv[4];
  #pragma unroll
  for (int j = 0; j < 4; ++j) bv[j] = bias[n0 + wc*64 + j*16 + lr];

  if (MODE == 0) {
    const int head = ny;
    const int sbase = txt ? (m0 - S_IMG) : (m0 + S_TXT);
    if (wsel == 2) {
      __bf16* Vt = (__bf16*)ga.O0[2];
      #pragma unroll
      for (int i = 0; i < 4; ++i) {
        const int s0 = sbase + wr*64 + i*16 + g*4;
        #pragma unroll
        for (int j = 0; j < 4; ++j) {
          const int hd = wc*64 + j*16 + lr;
          bf16x4 pk;
          #pragma unroll
          for (int r = 0; r < 4; ++r) pk[r] = (__bf16)(acc[i][j][r] + bv[j]);
          *(bf16x4*)(Vt + ((size_t)(head * HDIM + hd)) * S_TOT + s0) = pk;
        }
      }
    } else {
      __bf16* Qp = (__bf16*)ga.O0[wsel];
      #pragma unroll
      for (int i = 0; i < 4; ++i)
        #pragma unroll
        for (int j = 0; j < 4; ++j)
          #pragma unroll
          for (int r = 0; r < 4; ++r) {
            int s  = sbase + wr*64 + i*16 + g*4 + r;
            int hd = wc*64 + j*16 + lr;
            Qp[((size_t)head * S_TOT + s) * HDIM + hd] = (__bf16)(acc[i][j][r] + bv[j]);
          }
    }
  } else {
    float* Cf = (float*)(txt ? ga.O1[0] : ga.O0[0]);
    const int rbase = txt ? m0 : (m0 - S_TXT);
    #pragma unroll
    for (int i = 0; i < 4; ++i)
      #pragma unroll
      for (int j = 0; j < 4; ++j)
        #pragma unroll
        for (int r = 0; r < 4; ++r) {
          int m = rbase + wr*64 + i*16 + g*4 + r;
          int n = n0 + wc*64 + j*16 + lr;
          Cf[(size_t)m * DMODEL + n] = acc[i][j][r] + bv[j];
        }
  }
}

// ---------------- r9 in-flight-cvt GEMM (fallback when ws is small) ----------------
struct GArgs {
  const __bf16* A;
  const float* W0[3]; const float* W1[3];
  const float* b0[3]; const float* b1[3];
  void* O0[3]; void* O1[3];
};

#define NT 48

template<int MODE>
__global__ __launch_bounds__(256, 1) void gemm_all(GArgs ga) {
  const int tid = threadIdx.x;
  const int lane = tid & 63, wave = tid >> 6;
  const int wr = wave >> 1, wc = wave & 1;
  const int g = lane >> 4, lr = lane & 15;
  const int x7 = lr & 7;

  const int hw = (int)blockIdx.x;
  const int xcd = hw & 7, idx = hw >> 3;
  const int bx = idx % 18;
  const int nglob = (MODE == 0) ? (xcd * 9 + idx / 18) : (xcd * 3 + idx / 18);
  const int wsel = (MODE == 0) ? nglob / 24 : 0;
  const int ny   = (MODE == 0) ? nglob % 24 : nglob;
  const int m0 = bx * 128;
  const int n0 = ny * 128;
  const bool txt = (MODE == 0) ? (m0 >= S_IMG) : (m0 < S_TXT);
  const float* Wf   = txt ? ga.W1[wsel] : ga.W0[wsel];
  const float* bias = txt ? ga.b1[wsel] : ga.b0[wsel];

  __shared__ __align__(16) __bf16 As[2][128 * 64];
  __shared__ __align__(16) __bf16 Bs[128 * 64];

  const int sr8 = lane >> 3;
  const int sch = (lane & 7) ^ sr8;
  const __bf16* Ap = ga.A + (size_t)(m0 + wave * 8 + sr8) * DMODEL + sch * 8;

  const int wrow = tid >> 3;
  const int wch  = tid & 7;
  const float* Bp = Wf + (size_t)(n0 + wrow) * DMODEL + wch * 8;
  const int bwoff = wrow * 128 + ((wch ^ (wrow & 7)) << 4);

  f32x4 acc[4][4];
  #pragma unroll
  for (int i = 0; i < 4; ++i)
    #pragma unroll
    for (int j = 0; j < 4; ++j) acc[i][j] = (f32x4){0.f,0.f,0.f,0.f};

  f32x4 pre[4][2];

#define VSEP asm volatile("" ::: "memory")
#define ISSUE_A(kt, buf) { \
    const __bf16* Apk = Ap + (kt) * 64; \
    char* dst = (char*)(&As[(buf)][0]) + wave * 1024; \
    _Pragma("unroll") \
    for (int i_ = 0; i_ < 4; ++i_) \
      __builtin_amdgcn_global_load_lds( \
          (const __attribute__((address_space(1))) void*)(Apk + (size_t)i_ * 32 * DMODEL), \
          (__attribute__((address_space(3))) void*)(dst + i_ * 4096), 16, 0, 0); }
#define ISSUE_B(kt) { \
    const float* Bpk = Bp + (kt) * 64; \
    _Pragma("unroll") \
    for (int p_ = 0; p_ < 4; ++p_) { \
      pre[p_][0] = *(const f32x4*)(Bpk + (size_t)p_ * 32 * DMODEL); \
      pre[p_][1] = *(const f32x4*)(Bpk + (size_t)p_ * 32 * DMODEL + 4); } }
#define WRITE_B() { \
    _Pragma("unroll") \
    for (int p_ = 0; p_ < 4; ++p_) { \
      bf16x8 bw_; \
      _Pragma("unroll") \
      for (int j_ = 0; j_ < 4; ++j_) { \
        bw_[j_]     = (__bf16)pre[p_][0][j_]; \
        bw_[4 + j_] = (__bf16)pre[p_][1][j_]; } \
      *(bf16x8*)((char*)Bs + p_ * 4096 + bwoff) = bw_; } }
#define COMPUTE(buf) { \
    _Pragma("unroll") \
    for (int ks_ = 0; ks_ < 2; ++ks_) { \
      bf16x8 af_[4], bf_[4]; \
      _Pragma("unroll") \
      for (int i_ = 0; i_ < 4; ++i_) \
        af_[i_] = *(const bf16x8*)((char*)(&As[(buf)][0]) + (wr*64 + i_*16 + lr) * 128 + (((ks_*4 + g) ^ x7) << 4)); \
      _Pragma("unroll") \
      for (int j_ = 0; j_ < 4; ++j_) \
        bf_[j_] = *(const bf16x8*)((char*)Bs + (wc*64 + j_*16 + lr) * 128 + (((ks_*4 + g) ^ x7) << 4)); \
      __builtin_amdgcn_s_setprio(1); \
      _Pragma("unroll") \
      for (int i_ = 0; i_ < 4; ++i_) \
        _Pragma("unroll") \
        for (int j_ = 0; j_ < 4; ++j_) \
          acc[i_][j_] = mfma16(af_[i_], bf_[j_], acc[i_][j_]); \
      __builtin_amdgcn_s_setprio(0); } }

  ISSUE_B(0);        VSEP;
  ISSUE_A(0, 0);     VSEP;
  asm volatile("s_waitcnt vmcnt(4)" ::: "memory");
  WRITE_B();
  asm volatile("s_waitcnt vmcnt(0) lgkmcnt(0)" ::: "memory");
  __builtin_amdgcn_s_barrier();
  VSEP;

  for (int t = 0; t < NT - 2; t += 2) {
    ISSUE_A(t + 1, 1);  VSEP;
    ISSUE_B(t + 1);     VSEP;
    COMPUTE(0);
    __builtin_amdgcn_s_barrier();
    asm volatile("s_waitcnt vmcnt(0)" ::: "memory");
    WRITE_B();
    asm volatile("s_waitcnt lgkmcnt(0)" ::: "memory");
    __builtin_amdgcn_s_barrier();
    VSEP;
    ISSUE_A(t + 2, 0);  VSEP;
    ISSUE_B(t + 2);     VSEP;
    COMPUTE(1);
    __builtin_amdgcn_s_barrier();
    asm volatile("s_waitcnt vmcnt(0)" ::: "memory");
    WRITE_B();
    asm volatile("s_waitcnt lgkmcnt(0)" ::: "memory");
    __builtin_amdgcn_s_barrier();
    VSEP;
  }

  ISSUE_A(NT - 1, 1);  VSEP;
  ISSUE_B(NT - 1);     VSEP;
  COMPUTE(0);
  __builtin_amdgcn_s_barrier();
  asm volatile("s_waitcnt vmcnt(0)" ::: "memory");
  WRITE_B();
  asm volatile("s_waitcnt lgkmcnt(0)" ::: "memory");
  __builtin_amdgcn_s_barrier();
  COMPUTE(1);

#undef VSEP
#undef ISSUE_A
#undef ISSUE_B
#undef WRITE_B
#undef COMPUTE

  float bv[4];
  #pragma unroll
  for (int j = 0; j < 4; ++j) bv[j] = bias[n0 + wc*64 + j*16 + lr];

  if (MODE == 0) {
    __bf16* Qp = (__bf16*)(txt ? ga.O1[wsel] : ga.O0[wsel]);
    const int sbase = txt ? (m0 - S_IMG) : (m0 + S_TXT);
    #pragma unroll
    for (int i = 0; i < 4; ++i)
      #pragma unroll
      for (int j = 0; j < 4; ++j)
        #pragma unroll
        for (int r = 0; r < 4; ++r) {
          int s  = sbase + wr*64 + i*16 + g*4 + r;
          int hd = wc*64 + j*16 + lr;
          Qp[((size_t)ny * S_TOT + s) * HDIM + hd] = (__bf16)(acc[i][j][r] + bv[j]);
        }
  } else {
    float* Cf = (float*)(txt ? ga.O1[0] : ga.O0[0]);
    const int rbase = txt ? m0 : (m0 - S_TXT);
    #pragma unroll
    for (int i = 0; i < 4; ++i)
      #pragma unroll
      for (int j = 0; j < 4; ++j)
        #pragma unroll
        for (int r = 0; r < 4; ++r) {
          int m = rbase + wr*64 + i*16 + g*4 + r;
          int n = n0 + wc*64 + j*16 + lr;
          Cf[(size_t)m * DMODEL + n] = acc[i][j][r] + bv[j];
        }
  }
}

// -------- flash attention: QBLK=128 (8 waves), K/V staging amortized 2x --------
// grid 432 = 8 XCD x (3 heads x 18 qtiles); 512 thr = 8 waves x 16 q-rows.
__global__ __launch_bounds__(512, 2) void flash_attn(
    const __bf16* __restrict__ Qg, const __bf16* __restrict__ Kg,
    const __bf16* __restrict__ Vt, __bf16* __restrict__ Og)
{
  const int bid = (int)blockIdx.x;
  const int xcd = bid & 7, bidx = bid >> 3;       // 432 = 8 x 54
  const int h  = xcd * 3 + bidx / 18;             // 3 heads per XCD
  const int q0 = (bidx % 18) * 128;
  const int tid = threadIdx.x;
  const int lane = tid & 63, wave = tid >> 6;     // wave 0..7
  const int g = lane >> 4, lr = lane & 15;
  const int x7 = lr & 7;

  __shared__ __align__(16) __bf16 Kl[64 * 128];   // 16KB [kv][d]
  __shared__ __align__(16) __bf16 Vl[128 * 64];   // 16KB [d][kv]
  __shared__ __align__(16) __bf16 Pl[8][16 * 64]; // 16KB per-wave [q][kv]
  char* Kc = (char*)Kl;
  char* Vc = (char*)Vl;
  char* Pc = (char*)&Pl[wave][0];

  bf16x8 ones;
  #pragma unroll
  for (int j = 0; j < 8; ++j) ones[j] = (__bf16)1.0f;

  bf16x8 qf[4];
  {
    const __bf16* qp = Qg + ((size_t)h * S_TOT + q0 + wave*16 + lr) * HDIM + g * 8;
    #pragma unroll
    for (int kb = 0; kb < 4; ++kb) qf[kb] = *(const bf16x8*)(qp + kb * 32);
  }

  f32x4 acc[8];
  #pragma unroll
  for (int i = 0; i < 8; ++i) acc[i] = (f32x4){0.f,0.f,0.f,0.f};
  float lrow[4] = {0.f, 0.f, 0.f, 0.f};

  const int krow = tid >> 4, kc = tid & 15;       // krow 0..31
  const int vrow = tid >> 3, vc = tid & 7;        // vrow 0..63
  const __bf16* Kbase = Kg + (size_t)h * S_TOT * HDIM;
  const __bf16* Vbase = Vt + (size_t)h * HDIM * S_TOT;

  const int kwoff = krow * 256 + ((kc ^ (krow & 7)) << 4);
  const int vwoff = vrow * 128 + ((vc ^ (vrow & 7)) << 4);

  bf16x8 kreg[2], vreg[2];
  #pragma unroll
  for (int i = 0; i < 2; ++i) {
    kreg[i] = *(const bf16x8*)(Kbase + (size_t)(i*32 + krow) * HDIM + kc * 8);
    vreg[i] = *(const bf16x8*)(Vbase + (size_t)(i*64 + vrow) * S_TOT + vc * 8);
  }

  for (int t = 0; t < S_TOT / 64; ++t) {
    asm volatile("" ::: "memory");
    __builtin_amdgcn_s_barrier();
    asm volatile("" ::: "memory");
    #pragma unroll
    for (int i = 0; i < 2; ++i) {
      *(bf16x8*)(Kc + kwoff + i * 8192) = kreg[i];
      *(bf16x8*)(Vc + vwoff + i * 8192) = vreg[i];
    }
    if (t + 1 < S_TOT / 64) {
      int kv1 = (t + 1) * 64;
      #pragma unroll
      for (int i = 0; i < 2; ++i) {
        kreg[i] = *(const bf16x8*)(Kbase + (size_t)(kv1 + i*32 + krow) * HDIM + kc * 8);
        vreg[i] = *(const bf16x8*)(Vbase + (size_t)(i*64 + vrow) * S_TOT + kv1 + vc * 8);
      }
    }
    asm volatile("s_waitcnt lgkmcnt(0)" ::: "memory");
    __builtin_amdgcn_s_barrier();
    asm volatile("" ::: "memory");

    f32x4 sc[4];
    __builtin_amdgcn_s_setprio(1);
    #pragma unroll
    for (int kb = 0; kb < 4; ++kb) {
      f32x4 s4 = (f32x4){0.f,0.f,0.f,0.f};
      #pragma unroll
      for (int dk = 0; dk < 4; ++dk) {
        bf16x8 kf = *(const bf16x8*)(Kc + (kb*16 + lr) * 256 + (((dk*4 + g) ^ x7) << 4));
        s4 = mfma16(qf[dk], kf, s4);
      }
      sc[kb] = s4;
    }
    __builtin_amdgcn_s_setprio(0);

    #pragma unroll
    for (int kb = 0; kb < 4; ++kb)
      #pragma unroll
      for (int r = 0; r < 4; ++r)
        sc[kb][r] = fexp2(sc[kb][r]);

    #pragma unroll
    for (int kb = 0; kb < 4; ++kb)
      #pragma unroll
      for (int r = 0; r < 4; ++r) {
        int row = g*4 + r;
        *(__bf16*)(Pc + (((row * 128) + (kb*16 + lr) * 2) ^ ((row & 7) << 4))) = (__bf16)sc[kb][r];
      }

    bf16x8 ap0 = *(const bf16x8*)(Pc + ((lr * 128 + g * 16) ^ (x7 << 4)));
    bf16x8 ap1 = *(const bf16x8*)(Pc + ((lr * 128 + (4 + g) * 16) ^ (x7 << 4)));

    f32x4 ls = (f32x4){0.f, 0.f, 0.f, 0.f};
    ls = mfma16(ap0, ones, ls);
    ls = mfma16(ap1, ones, ls);
    #pragma unroll
    for (int r = 0; r < 4; ++r) lrow[r] += ls[r];

    __builtin_amdgcn_s_setprio(1);
    #pragma unroll
    for (int db = 0; db < 8; ++db) {
      bf16x8 v0 = *(const bf16x8*)(Vc + (db*16 + lr) * 128 + ((g ^ x7) << 4));
      bf16x8 v1 = *(const bf16x8*)(Vc + (db*16 + lr) * 128 + (((4 + g) ^ x7) << 4));
      acc[db] = mfma16(ap0, v0, acc[db]);
      acc[db] = mfma16(ap1, v1, acc[db]);
    }
    __builtin_amdgcn_s_setprio(0);
  }

  float rinv[4];
  #pragma unroll
  for (int r = 0; r < 4; ++r) rinv[r] = 1.f / lrow[r];
  #pragma unroll
  for (int db = 0; db < 8; ++db)
    #pragma unroll
    for (int r = 0; r < 4; ++r) {
      int s = q0 + wave*16 + g*4 + r;
      Og[(size_t)s * DMODEL + h * HDIM + db*16 + lr] = (__bf16)(acc[db][r] * rinv[r]);
    }
}

// ---------------- host ----------------
extern "C" void kernel_launch(void* const* d_in, const int* in_sizes, int n_in,
                              void* d_out, int out_size, void* d_ws, size_t ws_size,
                              hipStream_t stream) {
  const float* x_img   = (const float*)d_in[0];
  const float* x_txt   = (const float*)d_in[1];
  const float* img_cos = (const float*)d_in[2];
  const float* img_sin = (const float*)d_in[3];
  const float* txt_cos = (const float*)d_in[4];
  const float* txt_sin = (const float*)d_in[5];
  const float* Wq  = (const float*)d_in[6];  const float* bq  = (const float*)d_in[7];
  const float* Wk  = (const float*)d_in[8];  const float* bk  = (const float*)d_in[9];
  const float* Wv  = (const float*)d_in[10]; const float* bv  = (const float*)d_in[11];
  const float* Waq = (const float*)d_in[12]; const float* baq = (const float*)d_in[13];
  const float* Wak = (const float*)d_in[14]; const float* bak = (const float*)d_in[15];
  const float* Wav = (const float*)d_in[16]; const float* bav = (const float*)d_in[17];
  const float* Wo  = (const float*)d_in[18]; const float* bo  = (const float*)d_in[19];
  const float* Wao = (const float*)d_in[20]; const float* bao = (const float*)d_in[21];

  __bf16* ws = (__bf16*)d_ws;
  __bf16* Qb  = ws;
  __bf16* Kb  = Qb + SZ_QKV;
  __bf16* Vb  = Kb + SZ_QKV;
  __bf16* Vtb = Vb + SZ_QKV;
  __bf16* AO  = Vtb + SZ_QKV;
  __bf16* XI  = AO + SZ_AO;          // [2304][3072]: rows 0..2047 img, 2048..2303 txt
  __bf16* XT  = XI + SZ_XIMG;
  __bf16* Wbf = XI + SZ_AO;          // weight slots (big path)

  const size_t need6 = (5 * SZ_QKV + SZ_AO + 6 * SZ_W) * sizeof(__bf16);  // ~198 MB
  const size_t need8 = (5 * SZ_QKV + SZ_AO + 8 * SZ_W) * sizeof(__bf16);  // ~236 MB
  const bool big8 = ws_size >= need8;
  const bool big  = ws_size >= need6;

  float* out_img = (float*)d_out;
  float* out_txt = out_img + (size_t)S_IMG * DMODEL;

  cvt_f32_bf16<<<dim3((unsigned)(SZ_XIMG/2048)), 256, 0, stream>>>(x_img, XI, (int)SZ_XIMG);
  cvt_f32_bf16<<<dim3((unsigned)(SZ_XTXT/2048)), 256, 0, stream>>>(x_txt, XT, (int)SZ_XTXT);

  if (big) {
    CWArgs cw{};
    const float* wsrc[8] = {Wq, Wk, Wv, Waq, Wak, Wav, Wo, Wao};
    const int nw = big8 ? 8 : 6;
    for (int i = 0; i < nw; ++i) { cw.s[i] = wsrc[i]; cw.d[i] = Wbf + (size_t)i * SZ_W; }
    cvt_w<<<dim3(1152, (unsigned)nw), 256, 0, stream>>>(cw);

    GBArgs gb{};
    gb.A = XI;
    gb.W0[0] = Wbf;            gb.W0[1] = Wbf + SZ_W;     gb.W0[2] = Wbf + 2*SZ_W;
    gb.W1[0] = Wbf + 3*SZ_W;   gb.W1[1] = Wbf + 4*SZ_W;   gb.W1[2] = Wbf + 5*SZ_W;
    gb.b0[0] = bq;  gb.b0[1] = bk;  gb.b0[2] = bv;
    gb.b1[0] = baq; gb.b1[1] = bak; gb.b1[2] = bav;
    gb.O0[0] = Qb;  gb.O0[1] = Kb;  gb.O0[2] = Vtb;   // V written transposed
    gb.O1[0] = Qb;  gb.O1[1] = Kb;  gb.O1[2] = Vtb;
    gemm_bf<0><<<dim3(1296), 256, 0, stream>>>(gb);
    rope_kernel<<<dim3(3456, 2), 256, 0, stream>>>(Qb, Kb, img_cos, img_sin, txt_cos, txt_sin);
  } else {
    GArgs gq{};
    gq.A = XI;
    gq.W0[0] = Wq;  gq.W0[1] = Wk;  gq.W0[2] = Wv;
    gq.W1[0] = Waq; gq.W1[1] = Wak; gq.W1[2] = Wav;
    gq.b0[0] = bq;  gq.b0[1] = bk;  gq.b0[2] = bv;
    gq.b1[0] = baq; gq.b1[1] = bak; gq.b1[2] = bav;
    gq.O0[0] = Qb;  gq.O0[1] = Kb;  gq.O0[2] = Vb;
    gq.O1[0] = Qb;  gq.O1[1] = Kb;  gq.O1[2] = Vb;
    gemm_all<0><<<dim3(1296), 256, 0, stream>>>(gq);
    rope_kernel<<<dim3(3456, 2), 256, 0, stream>>>(Qb, Kb, img_cos, img_sin, txt_cos, txt_sin);
    transpose_v<<<dim3(36, 24), 128, 0, stream>>>(Vb, Vtb);
  }

  flash_attn<<<dim3(432), 512, 0, stream>>>(Qb, Kb, Vtb, AO);

  if (big) {
    const __bf16 *WoB, *WaoB;
    if (big8) {
      WoB = Wbf + 6*SZ_W;  WaoB = Wbf + 7*SZ_W;
    } else {
      CWArgs cw{};
      cw.s[0] = Wo;  cw.d[0] = Wbf;
      cw.s[1] = Wao; cw.d[1] = Wbf + SZ_W;
      cvt_w<<<dim3(1152, 2), 256, 0, stream>>>(cw);
      WoB = Wbf;  WaoB = Wbf + SZ_W;
    }
    GBArgs go{};
    go.A = AO;
    go.W0[0] = WoB;       go.W1[0] = WaoB;
    go.b0[0] = bo;  go.b1[0] = bao;
    go.O0[0] = out_img; go.O1[0] = out_txt;
    gemm_bf<1><<<dim3(432), 256, 0, stream>>>(go);
  } else {
    GArgs go{};
    go.A = AO;
    go.W0[0] = Wo;  go.W1[0] = Wao;
    go.b0[0] = bo;  go.b1[0] = bao;
    go.O0[0] = out_img; go.O1[0] = out_txt;
    gemm_all<1><<<dim3(432), 256, 0, stream>>>(go);
  }

  (void)in_sizes; (void)n_in; (void)out_size;
}

// Round 22
// 388.584 us; speedup vs baseline: 1.0701x; 1.0701x over previous
//
#include <hip/hip_runtime.h>
#include <cstdint>
#include <cstddef>

typedef __bf16 bf16x8 __attribute__((ext_vector_type(8)));
typedef __bf16 bf16x4 __attribute__((ext_vector_type(4)));
typedef float  f32x4  __attribute__((ext_vector_type(4)));

#define S_TXT 256
#define S_IMG 2048
#define S_TOT 2304
#define NHEAD 24
#define HDIM  128
#define DMODEL 3072

static constexpr size_t SZ_QKV  = (size_t)NHEAD * S_TOT * HDIM;   // 7,077,888
static constexpr size_t SZ_AO   = (size_t)S_TOT * DMODEL;         // 7,077,888
static constexpr size_t SZ_XIMG = (size_t)S_IMG * DMODEL;
static constexpr size_t SZ_XTXT = (size_t)S_TXT * DMODEL;
static constexpr size_t SZ_W    = (size_t)DMODEL * DMODEL;        // 9,437,184

// 1/sqrt(128) * log2(e): flash softmax runs in base-2 (native v_exp_f32)
#define QSCALE (0.08838834764831845f * 1.4426950408889634f)

__device__ __forceinline__ f32x4 mfma16(bf16x8 a, bf16x8 b, f32x4 c) {
  return __builtin_amdgcn_mfma_f32_16x16x32_bf16(a, b, c, 0, 0, 0);
}

__device__ __forceinline__ float fexp2(float x) {
  return __builtin_amdgcn_exp2f(x);
}

// ---------------- fp32 -> bf16 convert (RNE) ----------------
__global__ __launch_bounds__(256) void cvt_f32_bf16(const float* __restrict__ in,
                                                    __bf16* __restrict__ out, int n) {
  int i = (blockIdx.x * 256 + threadIdx.x) * 8;
  if (i + 8 > n) return;
  f32x4 a = *(const f32x4*)(in + i);
  f32x4 b = *(const f32x4*)(in + i + 4);
  bf16x8 r;
  r[0]=(__bf16)a[0]; r[1]=(__bf16)a[1]; r[2]=(__bf16)a[2]; r[3]=(__bf16)a[3];
  r[4]=(__bf16)b[0]; r[5]=(__bf16)b[1]; r[6]=(__bf16)b[2]; r[7]=(__bf16)b[3];
  *(bf16x8*)(out + i) = r;
}

// ---------------- multi-weight fp32 -> bf16 (grid.y selects weight) ----------------
struct CWArgs { const float* s[6]; __bf16* d[6]; };
__global__ __launch_bounds__(256) void cvt_w(CWArgs a) {
  const float* in = a.s[blockIdx.y];
  __bf16* out = a.d[blockIdx.y];
  size_t i = ((size_t)blockIdx.x * 256 + threadIdx.x) * 8;
  f32x4 x = *(const f32x4*)(in + i);
  f32x4 y = *(const f32x4*)(in + i + 4);
  bf16x8 r;
  r[0]=(__bf16)x[0]; r[1]=(__bf16)x[1]; r[2]=(__bf16)x[2]; r[3]=(__bf16)x[3];
  r[4]=(__bf16)y[0]; r[5]=(__bf16)y[1]; r[6]=(__bf16)y[2]; r[7]=(__bf16)y[3];
  *(bf16x8*)(out + i) = r;
}

// ---------------- RoPE in-place; Q additionally pre-scaled by QSCALE ----------------
__global__ __launch_bounds__(256) void rope_kernel(__bf16* __restrict__ Qb, __bf16* __restrict__ Kb,
    const float* __restrict__ icos, const float* __restrict__ isin,
    const float* __restrict__ tcos, const float* __restrict__ tsin) {
  size_t idx = ((size_t)blockIdx.x * 256 + threadIdx.x) * 8;
  __bf16* X; float mult;
  if (blockIdx.y) { X = Kb; mult = 1.0f; }
  else            { X = Qb; mult = QSCALE; }
  int d = (int)(idx & 127);
  int s = (int)((idx >> 7) % S_TOT);
  const float *cp, *sp; int ss;
  if (s < S_TXT) { cp = tcos; sp = tsin; ss = s; }
  else           { cp = icos; sp = isin; ss = s - S_TXT; }
  const float* cb = cp + (size_t)ss * HDIM + d;
  const float* sb = sp + (size_t)ss * HDIM + d;
  f32x4 c0 = *(const f32x4*)(cb);
  f32x4 c1 = *(const f32x4*)(cb + 4);
  f32x4 s0 = *(const f32x4*)(sb);
  f32x4 s1 = *(const f32x4*)(sb + 4);
  bf16x8 x = *(const bf16x8*)(X + idx);
  float xf[8];
  #pragma unroll
  for (int j = 0; j < 8; ++j) xf[j] = (float)x[j];
  bf16x8 o;
  o[0] = (__bf16)((xf[0]*c0[0] - xf[1]*s0[0]) * mult);
  o[1] = (__bf16)((xf[1]*c0[1] + xf[0]*s0[1]) * mult);
  o[2] = (__bf16)((xf[2]*c0[2] - xf[3]*s0[2]) * mult);
  o[3] = (__bf16)((xf[3]*c0[3] + xf[2]*s0[3]) * mult);
  o[4] = (__bf16)((xf[4]*c1[0] - xf[5]*s1[0]) * mult);
  o[5] = (__bf16)((xf[5]*c1[1] + xf[4]*s1[1]) * mult);
  o[6] = (__bf16)((xf[6]*c1[2] - xf[7]*s1[2]) * mult);
  o[7] = (__bf16)((xf[7]*c1[3] + xf[6]*s1[3]) * mult);
  *(bf16x8*)(X + idx) = o;
}

// ---------------- V [h][s][d] -> Vt [h][d][s] (FALLBACK PATH ONLY) ----------------
__global__ __launch_bounds__(128) void transpose_v(const __bf16* __restrict__ V,
                                                   __bf16* __restrict__ Vt) {
  int h = blockIdx.y, s0 = blockIdx.x * 64, d = threadIdx.x;
  const __bf16* src = V + ((size_t)h * S_TOT + s0) * HDIM + d;
  __bf16 tmp[64];
  #pragma unroll
  for (int k = 0; k < 64; ++k) tmp[k] = src[(size_t)k * HDIM];
  __bf16* dst = Vt + ((size_t)h * HDIM + d) * S_TOT + s0;
  #pragma unroll
  for (int k = 0; k < 8; ++k) {
    bf16x8 v;
    #pragma unroll
    for (int j = 0; j < 8; ++j) v[j] = tmp[k*8 + j];
    *(bf16x8*)(dst + k*8) = v;
  }
}

// ================ pure-bf16 GEMM (m97-faithful), BM=BN=128, BK=64 ================
struct GBArgs {
  const __bf16* A;
  const __bf16* W0[3];
  const __bf16* W1[3];
  const float* b0[3]; const float* b1[3];
  void* O0[3]; void* O1[3];
};

template<int MODE>
__global__ __launch_bounds__(256) void gemm_bf(GBArgs ga) {
  const int tid = threadIdx.x;
  const int lane = tid & 63, wave = tid >> 6;
  const int wr = wave >> 1, wc = wave & 1;
  const int g = lane >> 4, lr = lane & 15;
  const int x7 = lr & 7;

  const int hw = (int)blockIdx.x;
  const int xcd = hw & 7, idx = hw >> 3;
  const int bx = idx % 18;
  const int nglob = (MODE == 0) ? (xcd * 9 + idx / 18) : (xcd * 3 + idx / 18);
  const int wsel = (MODE == 0) ? nglob / 24 : 0;
  const int ny   = (MODE == 0) ? nglob % 24 : nglob;
  const int m0 = bx * 128;
  const int n0 = ny * 128;
  const bool txt = (MODE == 0) ? (m0 >= S_IMG) : (m0 < S_TXT);
  const __bf16* Wf  = txt ? ga.W1[wsel] : ga.W0[wsel];
  const float* bias = txt ? ga.b1[wsel] : ga.b0[wsel];

  __shared__ __align__(16) __bf16 As[128 * 64];
  __shared__ __align__(16) __bf16 Bs[128 * 64];

  const int sr8 = lane >> 3;
  const int sch = (lane & 7) ^ sr8;
  const __bf16* Ap = ga.A + (size_t)(m0 + wave * 8 + sr8) * DMODEL + sch * 8;
  const __bf16* Bp = Wf   + (size_t)(n0 + wave * 8 + sr8) * DMODEL + sch * 8;

  f32x4 acc[4][4];
  #pragma unroll
  for (int i = 0; i < 4; ++i)
    #pragma unroll
    for (int j = 0; j < 4; ++j) acc[i][j] = (f32x4){0.f,0.f,0.f,0.f};

#define GLD(dst, srcp) { \
    _Pragma("unroll") \
    for (int i_ = 0; i_ < 4; ++i_) \
      __builtin_amdgcn_global_load_lds( \
          (const __attribute__((address_space(1))) void*)((srcp) + (size_t)i_ * 32 * DMODEL), \
          (__attribute__((address_space(3))) void*)((char*)(dst) + i_ * 4096 + wave * 1024), \
          16, 0, 0); }

  for (int kt = 0; kt < DMODEL / 64; ++kt) {
    GLD(As, Ap + kt * 64);
    GLD(Bs, Bp + kt * 64);
    __syncthreads();
    #pragma unroll
    for (int ks = 0; ks < 2; ++ks) {
      bf16x8 af[4], bf[4];
      #pragma unroll
      for (int i = 0; i < 4; ++i)
        af[i] = *(const bf16x8*)((char*)As + (wr*64 + i*16 + lr) * 128 + (((ks*4 + g) ^ x7) << 4));
      #pragma unroll
      for (int j = 0; j < 4; ++j)
        bf[j] = *(const bf16x8*)((char*)Bs + (wc*64 + j*16 + lr) * 128 + (((ks*4 + g) ^ x7) << 4));
      __builtin_amdgcn_s_setprio(1);
      #pragma unroll
      for (int i = 0; i < 4; ++i)
        #pragma unroll
        for (int j = 0; j < 4; ++j)
          acc[i][j] = mfma16(af[i], bf[j], acc[i][j]);
      __builtin_amdgcn_s_setprio(0);
    }
    __syncthreads();
  }
#undef GLD

  float bv[4];
  #pragma unroll
  for (int j = 0; j < 4; ++j) bv[j] = bias[n0 + wc*64 + j*16 + lr];

  if (MODE == 0) {
    const int head = ny;
    const int sbase = txt ? (m0 - S_IMG) : (m0 + S_TXT);
    if (wsel == 2) {
      __bf16* Vt = (__bf16*)ga.O0[2];
      #pragma unroll
      for (int i = 0; i < 4; ++i) {
        const int s0 = sbase + wr*64 + i*16 + g*4;
        #pragma unroll
        for (int j = 0; j < 4; ++j) {
          const int hd = wc*64 + j*16 + lr;
          bf16x4 pk;
          #pragma unroll
          for (int r = 0; r < 4; ++r) pk[r] = (__bf16)(acc[i][j][r] + bv[j]);
          *(bf16x4*)(Vt + ((size_t)(head * HDIM + hd)) * S_TOT + s0) = pk;
        }
      }
    } else {
      __bf16* Qp = (__bf16*)ga.O0[wsel];
      #pragma unroll
      for (int i = 0; i < 4; ++i)
        #pragma unroll
        for (int j = 0; j < 4; ++j)
          #pragma unroll
          for (int r = 0; r < 4; ++r) {
            int s  = sbase + wr*64 + i*16 + g*4 + r;
            int hd = wc*64 + j*16 + lr;
            Qp[((size_t)head * S_TOT + s) * HDIM + hd] = (__bf16)(acc[i][j][r] + bv[j]);
          }
    }
  } else {
    float* Cf = (float*)(txt ? ga.O1[0] : ga.O0[0]);
    const int rbase = txt ? m0 : (m0 - S_TXT);
    #pragma unroll
    for (int i = 0; i < 4; ++i)
      #pragma unroll
      for (int j = 0; j < 4; ++j)
        #pragma unroll
        for (int r = 0; r < 4; ++r) {
          int m = rbase + wr*64 + i*16 + g*4 + r;
          int n = n0 + wc*64 + j*16 + lr;
          Cf[(size_t)m * DMODEL + n] = acc[i][j][r] + bv[j];
        }
  }
}

// ---------------- r9 in-flight-cvt GEMM (fallback when ws is small) ----------------
struct GArgs {
  const __bf16* A;
  const float* W0[3]; const float* W1[3];
  const float* b0[3]; const float* b1[3];
  void* O0[3]; void* O1[3];
};

#define NT 48

template<int MODE>
__global__ __launch_bounds__(256, 1) void gemm_all(GArgs ga) {
  const int tid = threadIdx.x;
  const int lane = tid & 63, wave = tid >> 6;
  const int wr = wave >> 1, wc = wave & 1;
  const int g = lane >> 4, lr = lane & 15;
  const int x7 = lr & 7;

  const int hw = (int)blockIdx.x;
  const int xcd = hw & 7, idx = hw >> 3;
  const int bx = idx % 18;
  const int nglob = (MODE == 0) ? (xcd * 9 + idx / 18) : (xcd * 3 + idx / 18);
  const int wsel = (MODE == 0) ? nglob / 24 : 0;
  const int ny   = (MODE == 0) ? nglob % 24 : nglob;
  const int m0 = bx * 128;
  const int n0 = ny * 128;
  const bool txt = (MODE == 0) ? (m0 >= S_IMG) : (m0 < S_TXT);
  const float* Wf   = txt ? ga.W1[wsel] : ga.W0[wsel];
  const float* bias = txt ? ga.b1[wsel] : ga.b0[wsel];

  __shared__ __align__(16) __bf16 As[2][128 * 64];
  __shared__ __align__(16) __bf16 Bs[128 * 64];

  const int sr8 = lane >> 3;
  const int sch = (lane & 7) ^ sr8;
  const __bf16* Ap = ga.A + (size_t)(m0 + wave * 8 + sr8) * DMODEL + sch * 8;

  const int wrow = tid >> 3;
  const int wch  = tid & 7;
  const float* Bp = Wf + (size_t)(n0 + wrow) * DMODEL + wch * 8;
  const int bwoff = wrow * 128 + ((wch ^ (wrow & 7)) << 4);

  f32x4 acc[4][4];
  #pragma unroll
  for (int i = 0; i < 4; ++i)
    #pragma unroll
    for (int j = 0; j < 4; ++j) acc[i][j] = (f32x4){0.f,0.f,0.f,0.f};

  f32x4 pre[4][2];

#define VSEP asm volatile("" ::: "memory")
#define ISSUE_A(kt, buf) { \
    const __bf16* Apk = Ap + (kt) * 64; \
    char* dst = (char*)(&As[(buf)][0]) + wave * 1024; \
    _Pragma("unroll") \
    for (int i_ = 0; i_ < 4; ++i_) \
      __builtin_amdgcn_global_load_lds( \
          (const __attribute__((address_space(1))) void*)(Apk + (size_t)i_ * 32 * DMODEL), \
          (__attribute__((address_space(3))) void*)(dst + i_ * 4096), 16, 0, 0); }
#define ISSUE_B(kt) { \
    const float* Bpk = Bp + (kt) * 64; \
    _Pragma("unroll") \
    for (int p_ = 0; p_ < 4; ++p_) { \
      pre[p_][0] = *(const f32x4*)(Bpk + (size_t)p_ * 32 * DMODEL); \
      pre[p_][1] = *(const f32x4*)(Bpk + (size_t)p_ * 32 * DMODEL + 4); } }
#define WRITE_B() { \
    _Pragma("unroll") \
    for (int p_ = 0; p_ < 4; ++p_) { \
      bf16x8 bw_; \
      _Pragma("unroll") \
      for (int j_ = 0; j_ < 4; ++j_) { \
        bw_[j_]     = (__bf16)pre[p_][0][j_]; \
        bw_[4 + j_] = (__bf16)pre[p_][1][j_]; } \
      *(bf16x8*)((char*)Bs + p_ * 4096 + bwoff) = bw_; } }
#define COMPUTE(buf) { \
    _Pragma("unroll") \
    for (int ks_ = 0; ks_ < 2; ++ks_) { \
      bf16x8 af_[4], bf_[4]; \
      _Pragma("unroll") \
      for (int i_ = 0; i_ < 4; ++i_) \
        af_[i_] = *(const bf16x8*)((char*)(&As[(buf)][0]) + (wr*64 + i_*16 + lr) * 128 + (((ks_*4 + g) ^ x7) << 4)); \
      _Pragma("unroll") \
      for (int j_ = 0; j_ < 4; ++j_) \
        bf_[j_] = *(const bf16x8*)((char*)Bs + (wc*64 + j_*16 + lr) * 128 + (((ks_*4 + g) ^ x7) << 4)); \
      __builtin_amdgcn_s_setprio(1); \
      _Pragma("unroll") \
      for (int i_ = 0; i_ < 4; ++i_) \
        _Pragma("unroll") \
        for (int j_ = 0; j_ < 4; ++j_) \
          acc[i_][j_] = mfma16(af_[i_], bf_[j_], acc[i_][j_]); \
      __builtin_amdgcn_s_setprio(0); } }

  ISSUE_B(0);        VSEP;
  ISSUE_A(0, 0);     VSEP;
  asm volatile("s_waitcnt vmcnt(4)" ::: "memory");
  WRITE_B();
  asm volatile("s_waitcnt vmcnt(0) lgkmcnt(0)" ::: "memory");
  __builtin_amdgcn_s_barrier();
  VSEP;

  for (int t = 0; t < NT - 2; t += 2) {
    ISSUE_A(t + 1, 1);  VSEP;
    ISSUE_B(t + 1);     VSEP;
    COMPUTE(0);
    __builtin_amdgcn_s_barrier();
    asm volatile("s_waitcnt vmcnt(0)" ::: "memory");
    WRITE_B();
    asm volatile("s_waitcnt lgkmcnt(0)" ::: "memory");
    __builtin_amdgcn_s_barrier();
    VSEP;
    ISSUE_A(t + 2, 0);  VSEP;
    ISSUE_B(t + 2);     VSEP;
    COMPUTE(1);
    __builtin_amdgcn_s_barrier();
    asm volatile("s_waitcnt vmcnt(0)" ::: "memory");
    WRITE_B();
    asm volatile("s_waitcnt lgkmcnt(0)" ::: "memory");
    __builtin_amdgcn_s_barrier();
    VSEP;
  }

  ISSUE_A(NT - 1, 1);  VSEP;
  ISSUE_B(NT - 1);     VSEP;
  COMPUTE(0);
  __builtin_amdgcn_s_barrier();
  asm volatile("s_waitcnt vmcnt(0)" ::: "memory");
  WRITE_B();
  asm volatile("s_waitcnt lgkmcnt(0)" ::: "memory");
  __builtin_amdgcn_s_barrier();
  COMPUTE(1);

#undef VSEP
#undef ISSUE_A
#undef ISSUE_B
#undef WRITE_B
#undef COMPUTE

  float bv[4];
  #pragma unroll
  for (int j = 0; j < 4; ++j) bv[j] = bias[n0 + wc*64 + j*16 + lr];

  if (MODE == 0) {
    __bf16* Qp = (__bf16*)(txt ? ga.O1[wsel] : ga.O0[wsel]);
    const int sbase = txt ? (m0 - S_IMG) : (m0 + S_TXT);
    #pragma unroll
    for (int i = 0; i < 4; ++i)
      #pragma unroll
      for (int j = 0; j < 4; ++j)
        #pragma unroll
        for (int r = 0; r < 4; ++r) {
          int s  = sbase + wr*64 + i*16 + g*4 + r;
          int hd = wc*64 + j*16 + lr;
          Qp[((size_t)ny * S_TOT + s) * HDIM + hd] = (__bf16)(acc[i][j][r] + bv[j]);
        }
  } else {
    float* Cf = (float*)(txt ? ga.O1[0] : ga.O0[0]);
    const int rbase = txt ? m0 : (m0 - S_TXT);
    #pragma unroll
    for (int i = 0; i < 4; ++i)
      #pragma unroll
      for (int j = 0; j < 4; ++j)
        #pragma unroll
        for (int r = 0; r < 4; ++r) {
          int m = rbase + wr*64 + i*16 + g*4 + r;
          int n = n0 + wc*64 + j*16 + lr;
          Cf[(size_t)m * DMODEL + n] = acc[i][j][r] + bv[j];
        }
  }
}

// -------- flash attention: QBLK=128 (8 waves), K/V staging amortized 2x --------
// grid 432 = 8 XCD x (3 heads x 18 qtiles); 512 thr = 8 waves x 16 q-rows.
__global__ __launch_bounds__(512, 2) void flash_attn(
    const __bf16* __restrict__ Qg, const __bf16* __restrict__ Kg,
    const __bf16* __restrict__ Vt, __bf16* __restrict__ Og)
{
  const int bid = (int)blockIdx.x;
  const int xcd = bid & 7, bidx = bid >> 3;       // 432 = 8 x 54
  const int h  = xcd * 3 + bidx / 18;             // 3 heads per XCD
  const int q0 = (bidx % 18) * 128;
  const int tid = threadIdx.x;
  const int lane = tid & 63, wave = tid >> 6;     // wave 0..7
  const int g = lane >> 4, lr = lane & 15;
  const int x7 = lr & 7;

  __shared__ __align__(16) __bf16 Kl[64 * 128];   // 16KB [kv][d]
  __shared__ __align__(16) __bf16 Vl[128 * 64];   // 16KB [d][kv]
  __shared__ __align__(16) __bf16 Pl[8][16 * 64]; // 16KB per-wave [q][kv]
  char* Kc = (char*)Kl;
  char* Vc = (char*)Vl;
  char* Pc = (char*)&Pl[wave][0];

  bf16x8 ones;
  #pragma unroll
  for (int j = 0; j < 8; ++j) ones[j] = (__bf16)1.0f;

  bf16x8 qf[4];
  {
    const __bf16* qp = Qg + ((size_t)h * S_TOT + q0 + wave*16 + lr) * HDIM + g * 8;
    #pragma unroll
    for (int kb = 0; kb < 4; ++kb) qf[kb] = *(const bf16x8*)(qp + kb * 32);
  }

  f32x4 acc[8];
  #pragma unroll
  for (int i = 0; i < 8; ++i) acc[i] = (f32x4){0.f,0.f,0.f,0.f};
  float lrow[4] = {0.f, 0.f, 0.f, 0.f};

  const int krow = tid >> 4, kc = tid & 15;       // krow 0..31
  const int vrow = tid >> 3, vc = tid & 7;        // vrow 0..63
  const __bf16* Kbase = Kg + (size_t)h * S_TOT * HDIM;
  const __bf16* Vbase = Vt + (size_t)h * HDIM * S_TOT;

  const int kwoff = krow * 256 + ((kc ^ (krow & 7)) << 4);
  const int vwoff = vrow * 128 + ((vc ^ (vrow & 7)) << 4);

  bf16x8 kreg[2], vreg[2];
  #pragma unroll
  for (int i = 0; i < 2; ++i) {
    kreg[i] = *(const bf16x8*)(Kbase + (size_t)(i*32 + krow) * HDIM + kc * 8);
    vreg[i] = *(const bf16x8*)(Vbase + (size_t)(i*64 + vrow) * S_TOT + vc * 8);
  }

  for (int t = 0; t < S_TOT / 64; ++t) {
    asm volatile("" ::: "memory");
    __builtin_amdgcn_s_barrier();
    asm volatile("" ::: "memory");
    #pragma unroll
    for (int i = 0; i < 2; ++i) {
      *(bf16x8*)(Kc + kwoff + i * 8192) = kreg[i];
      *(bf16x8*)(Vc + vwoff + i * 8192) = vreg[i];
    }
    if (t + 1 < S_TOT / 64) {
      int kv1 = (t + 1) * 64;
      #pragma unroll
      for (int i = 0; i < 2; ++i) {
        kreg[i] = *(const bf16x8*)(Kbase + (size_t)(kv1 + i*32 + krow) * HDIM + kc * 8);
        vreg[i] = *(const bf16x8*)(Vbase + (size_t)(i*64 + vrow) * S_TOT + kv1 + vc * 8);
      }
    }
    asm volatile("s_waitcnt lgkmcnt(0)" ::: "memory");
    __builtin_amdgcn_s_barrier();
    asm volatile("" ::: "memory");

    f32x4 sc[4];
    __builtin_amdgcn_s_setprio(1);
    #pragma unroll
    for (int kb = 0; kb < 4; ++kb) {
      f32x4 s4 = (f32x4){0.f,0.f,0.f,0.f};
      #pragma unroll
      for (int dk = 0; dk < 4; ++dk) {
        bf16x8 kf = *(const bf16x8*)(Kc + (kb*16 + lr) * 256 + (((dk*4 + g) ^ x7) << 4));
        s4 = mfma16(qf[dk], kf, s4);
      }
      sc[kb] = s4;
    }
    __builtin_amdgcn_s_setprio(0);

    #pragma unroll
    for (int kb = 0; kb < 4; ++kb)
      #pragma unroll
      for (int r = 0; r < 4; ++r)
        sc[kb][r] = fexp2(sc[kb][r]);

    #pragma unroll
    for (int kb = 0; kb < 4; ++kb)
      #pragma unroll
      for (int r = 0; r < 4; ++r) {
        int row = g*4 + r;
        *(__bf16*)(Pc + (((row * 128) + (kb*16 + lr) * 2) ^ ((row & 7) << 4))) = (__bf16)sc[kb][r];
      }

    bf16x8 ap0 = *(const bf16x8*)(Pc + ((lr * 128 + g * 16) ^ (x7 << 4)));
    bf16x8 ap1 = *(const bf16x8*)(Pc + ((lr * 128 + (4 + g) * 16) ^ (x7 << 4)));

    f32x4 ls = (f32x4){0.f, 0.f, 0.f, 0.f};
    ls = mfma16(ap0, ones, ls);
    ls = mfma16(ap1, ones, ls);
    #pragma unroll
    for (int r = 0; r < 4; ++r) lrow[r] += ls[r];

    __builtin_amdgcn_s_setprio(1);
    #pragma unroll
    for (int db = 0; db < 8; ++db) {
      bf16x8 v0 = *(const bf16x8*)(Vc + (db*16 + lr) * 128 + ((g ^ x7) << 4));
      bf16x8 v1 = *(const bf16x8*)(Vc + (db*16 + lr) * 128 + (((4 + g) ^ x7) << 4));
      acc[db] = mfma16(ap0, v0, acc[db]);
      acc[db] = mfma16(ap1, v1, acc[db]);
    }
    __builtin_amdgcn_s_setprio(0);
  }

  float rinv[4];
  #pragma unroll
  for (int r = 0; r < 4; ++r) rinv[r] = 1.f / lrow[r];
  #pragma unroll
  for (int db = 0; db < 8; ++db)
    #pragma unroll
    for (int r = 0; r < 4; ++r) {
      int s = q0 + wave*16 + g*4 + r;
      Og[(size_t)s * DMODEL + h * HDIM + db*16 + lr] = (__bf16)(acc[db][r] * rinv[r]);
    }
}

// ---------------- host ----------------
extern "C" void kernel_launch(void* const* d_in, const int* in_sizes, int n_in,
                              void* d_out, int out_size, void* d_ws, size_t ws_size,
                              hipStream_t stream) {
  const float* x_img   = (const float*)d_in[0];
  const float* x_txt   = (const float*)d_in[1];
  const float* img_cos = (const float*)d_in[2];
  const float* img_sin = (const float*)d_in[3];
  const float* txt_cos = (const float*)d_in[4];
  const float* txt_sin = (const float*)d_in[5];
  const float* Wq  = (const float*)d_in[6];  const float* bq  = (const float*)d_in[7];
  const float* Wk  = (const float*)d_in[8];  const float* bk  = (const float*)d_in[9];
  const float* Wv  = (const float*)d_in[10]; const float* bv  = (const float*)d_in[11];
  const float* Waq = (const float*)d_in[12]; const float* baq = (const float*)d_in[13];
  const float* Wak = (const float*)d_in[14]; const float* bak = (const float*)d_in[15];
  const float* Wav = (const float*)d_in[16]; const float* bav = (const float*)d_in[17];
  const float* Wo  = (const float*)d_in[18]; const float* bo  = (const float*)d_in[19];
  const float* Wao = (const float*)d_in[20]; const float* bao = (const float*)d_in[21];

  __bf16* ws = (__bf16*)d_ws;
  __bf16* Qb  = ws;
  __bf16* Kb  = Qb + SZ_QKV;
  __bf16* Vb  = Kb + SZ_QKV;
  __bf16* Vtb = Vb + SZ_QKV;
  __bf16* AO  = Vtb + SZ_QKV;
  __bf16* XI  = AO + SZ_AO;          // [2304][3072]: rows 0..2047 img, 2048..2303 txt
  __bf16* XT  = XI + SZ_XIMG;
  __bf16* Wbf = XI + SZ_AO;          // 6 bf16 weight slots (big path only)

  const size_t need_big = (5 * SZ_QKV + SZ_AO + 6 * SZ_W) * sizeof(__bf16);  // ~198 MB
  const bool big = ws_size >= need_big;

  float* out_img = (float*)d_out;
  float* out_txt = out_img + (size_t)S_IMG * DMODEL;

  cvt_f32_bf16<<<dim3((unsigned)(SZ_XIMG/2048)), 256, 0, stream>>>(x_img, XI, (int)SZ_XIMG);
  cvt_f32_bf16<<<dim3((unsigned)(SZ_XTXT/2048)), 256, 0, stream>>>(x_txt, XT, (int)SZ_XTXT);

  if (big) {
    CWArgs cw{};
    const float* wsrc[6] = {Wq, Wk, Wv, Waq, Wak, Wav};
    for (int i = 0; i < 6; ++i) { cw.s[i] = wsrc[i]; cw.d[i] = Wbf + (size_t)i * SZ_W; }
    cvt_w<<<dim3((unsigned)(SZ_W/2048), 6), 256, 0, stream>>>(cw);

    GBArgs gb{};
    gb.A = XI;
    gb.W0[0] = Wbf;            gb.W0[1] = Wbf + SZ_W;     gb.W0[2] = Wbf + 2*SZ_W;
    gb.W1[0] = Wbf + 3*SZ_W;   gb.W1[1] = Wbf + 4*SZ_W;   gb.W1[2] = Wbf + 5*SZ_W;
    gb.b0[0] = bq;  gb.b0[1] = bk;  gb.b0[2] = bv;
    gb.b1[0] = baq; gb.b1[1] = bak; gb.b1[2] = bav;
    gb.O0[0] = Qb;  gb.O0[1] = Kb;  gb.O0[2] = Vtb;   // V written transposed
    gb.O1[0] = Qb;  gb.O1[1] = Kb;  gb.O1[2] = Vtb;
    gemm_bf<0><<<dim3(1296), 256, 0, stream>>>(gb);
    rope_kernel<<<dim3(3456, 2), 256, 0, stream>>>(Qb, Kb, img_cos, img_sin, txt_cos, txt_sin);
  } else {
    GArgs gq{};
    gq.A = XI;
    gq.W0[0] = Wq;  gq.W0[1] = Wk;  gq.W0[2] = Wv;
    gq.W1[0] = Waq; gq.W1[1] = Wak; gq.W1[2] = Wav;
    gq.b0[0] = bq;  gq.b0[1] = bk;  gq.b0[2] = bv;
    gq.b1[0] = baq; gq.b1[1] = bak; gq.b1[2] = bav;
    gq.O0[0] = Qb;  gq.O0[1] = Kb;  gq.O0[2] = Vb;
    gq.O1[0] = Qb;  gq.O1[1] = Kb;  gq.O1[2] = Vb;
    gemm_all<0><<<dim3(1296), 256, 0, stream>>>(gq);
    rope_kernel<<<dim3(3456, 2), 256, 0, stream>>>(Qb, Kb, img_cos, img_sin, txt_cos, txt_sin);
    transpose_v<<<dim3(36, 24), 128, 0, stream>>>(Vb, Vtb);
  }

  flash_attn<<<dim3(432), 512, 0, stream>>>(Qb, Kb, Vtb, AO);

  if (big) {
    CWArgs cw{};
    cw.s[0] = Wo;  cw.d[0] = Wbf;
    cw.s[1] = Wao; cw.d[1] = Wbf + SZ_W;
    cvt_w<<<dim3((unsigned)(SZ_W/2048), 2), 256, 0, stream>>>(cw);

    GBArgs go{};
    go.A = AO;
    go.W0[0] = Wbf;       go.W1[0] = Wbf + SZ_W;
    go.b0[0] = bo;  go.b1[0] = bao;
    go.O0[0] = out_img; go.O1[0] = out_txt;
    gemm_bf<1><<<dim3(432), 256, 0, stream>>>(go);
  } else {
    GArgs go{};
    go.A = AO;
    go.W0[0] = Wo;  go.W1[0] = Wao;
    go.b0[0] = bo;  go.b1[0] = bao;
    go.O0[0] = out_img; go.O1[0] = out_txt;
    gemm_all<1><<<dim3(432), 256, 0, stream>>>(go);
  }

  (void)in_sizes; (void)n_in; (void)out_size;
}